// Round 1
// baseline (363.182 us; speedup 1.0000x reference)
//
#include <hip/hip_runtime.h>
#include <math.h>

// Problem constants (from reference setup_inputs)
constexpr int B = 4;
constexpr int N = 512;     // rois per batch
constexpr int C = 256;     // channels
constexpr int H = 256;
constexpr int W = 256;
constexpr int NPT = 5;     // center, front, back, left, right
// xs = (x - (-51.2)) / 0.1 / 4  ==  (x + 51.2) * 2.5

__global__ __launch_bounds__(256)
void bev_extract_kernel(const float* __restrict__ feats,  // (B,C,H,W)
                        const float* __restrict__ rois,   // (B,N,7)
                        float* __restrict__ out)          // (B,N,NPT*C)
{
    const int bn = blockIdx.x;          // 0 .. B*N-1
    const int b  = bn >> 9;             // / N (N=512)
    const int c  = threadIdx.x;         // channel, 0..255

    // ROI params (all threads read the same 7 floats -> L1 broadcast)
    const float* roi = rois + (size_t)bn * 7;
    const float cx = roi[0];
    const float cy = roi[1];
    const float dx = roi[3];
    const float dy = roi[4];
    const float ry = roi[6];

    float si, co;
    sincosf(ry, &si, &co);
    const float hx = 0.5f * dx;
    const float hy = 0.5f * dy;

    // 5 sample points: center, front, back, left, right
    // rot(a,b) = (a*c + b*s, -a*s + b*c)  [corners @ [[c,-s],[s,c]]]
    float px[NPT], py[NPT];
    px[0] = cx;            py[0] = cy;
    px[1] = cx - hx * co;  py[1] = cy + hx * si;   // front: rot(-hx, 0)
    px[2] = cx + hx * co;  py[2] = cy - hx * si;   // back : rot(+hx, 0)
    px[3] = cx - hy * si;  py[3] = cy - hy * co;   // left : rot(0, -hy)
    px[4] = cx + hy * si;  py[4] = cy + hy * co;   // right: rot(0, +hy)

    // Per-thread channel plane base: feats[b, c, :, :]
    const float* __restrict__ fp = feats + (((size_t)b * C + c) * H) * W;
    float* __restrict__ op = out + (size_t)bn * (NPT * C) + c;

#pragma unroll
    for (int p = 0; p < NPT; ++p) {
        const float xs = (px[p] + 51.2f) * 2.5f;
        const float ys = (py[p] + 51.2f) * 2.5f;
        const float xf = floorf(xs);
        const float yf = floorf(ys);
        int xi = (int)xf;
        int yi = (int)yf;
        const int x0 = min(max(xi, 0), W - 1);
        const int x1 = min(max(xi + 1, 0), W - 1);
        const int y0 = min(max(yi, 0), H - 1);
        const int y1 = min(max(yi + 1, 0), H - 1);

        const float x0f = (float)x0, x1f = (float)x1;
        const float y0f = (float)y0, y1f = (float)y1;
        const float wa = (x1f - xs) * (y1f - ys);
        const float wb = (x1f - xs) * (ys - y0f);
        const float wc = (xs - x0f) * (y1f - ys);
        const float wd = (xs - x0f) * (ys - y0f);

        const float Ia = fp[y0 * W + x0];
        const float Ib = fp[y1 * W + x0];
        const float Ic = fp[y0 * W + x1];
        const float Id = fp[y1 * W + x1];

        op[p * C] = Ia * wa + Ib * wb + Ic * wc + Id * wd;
    }
}

extern "C" void kernel_launch(void* const* d_in, const int* in_sizes, int n_in,
                              void* d_out, int out_size, void* d_ws, size_t ws_size,
                              hipStream_t stream) {
    const float* feats = (const float*)d_in[0];  // (B,C,H,W) f32
    const float* rois  = (const float*)d_in[1];  // (B,N,7)   f32
    float* out = (float*)d_out;                  // (B,N,NPT*C) f32

    dim3 grid(B * N);
    dim3 block(C);
    bev_extract_kernel<<<grid, block, 0, stream>>>(feats, rois, out);
}